// Round 7
// baseline (328.414 us; speedup 1.0000x reference)
//
#include <hip/hip_runtime.h>
#include <hip/hip_bf16.h>
#include <math.h>

constexpr int T   = 1024;
constexpr int H   = 2048;
constexpr int I   = 1024;
constexpr int E   = 8;
constexpr int NEZ = 16;   // E + Z
constexpr int TK  = 4;    // TOP_K

typedef short bf16x8 __attribute__((ext_vector_type(8)));
typedef float f32x4  __attribute__((ext_vector_type(4)));
typedef unsigned short u16;
typedef u16 u16x4 __attribute__((ext_vector_type(4)));
typedef u16 u16x8 __attribute__((ext_vector_type(8)));

#define VMCNT(n) asm volatile("s_waitcnt vmcnt(" #n ")" ::: "memory")

__device__ __forceinline__ u16 bf16rn(float x) {
  unsigned u = __builtin_bit_cast(unsigned, x);
  u = u + 0x7FFFu + ((u >> 16) & 1u);
  return (u16)(u >> 16);
}
__device__ __forceinline__ float bf16tof(u16 h) {
  return __builtin_bit_cast(float, (unsigned)h << 16);
}

// async global->LDS, 16B per lane; LDS dest = wave-uniform base + lane*16
__device__ __forceinline__ void g2l16(const void* g, void* l) {
  __builtin_amdgcn_global_load_lds(
      (const __attribute__((address_space(1))) unsigned int*)g,
      (__attribute__((address_space(3))) unsigned int*)l, 16, 0, 0);
}

// ---------------------------------------------------------------------------
// prep_x: split x into bf16 hi/lo planes [T][H]
// ---------------------------------------------------------------------------
__global__ __launch_bounds__(256) void prep_x_kernel(
    const float* __restrict__ x, u16* __restrict__ xh, u16* __restrict__ xl)
{
  const int idx = (blockIdx.x * 256 + threadIdx.x) * 4;
  const float4 v = *(const float4*)(x + idx);
  u16x4 h, l;
  const float vv[4] = {v.x, v.y, v.z, v.w};
#pragma unroll
  for (int i = 0; i < 4; i++) {
    const u16 hh = bf16rn(vv[i]);
    h[i] = hh;
    l[i] = bf16rn(vv[i] - bf16tof(hh));
  }
  *(u16x4*)(xh + idx) = h;
  *(u16x4*)(xl + idx) = l;
}

// ---------------------------------------------------------------------------
// Weight prep: convert+transpose one 32k x 64n tile into lane-ordered
// microtiles. Microtile (kt,ntg) = 1KB: lane L holds elems
// (n = ntg*16 + (L&15), k = kt*32 + (L>>4)*8 + j), j=0..7.
// Plane layout [e][kt][ntg][64][8].
// ---------------------------------------------------------------------------
template <int KDIM, int NDIM>
__device__ __forceinline__ void prep_tile(
    const float* __restrict__ src, u16* __restrict__ dh, u16* __restrict__ dl,
    int ei, int kt, int nb)
{
  const int k0 = kt * 32, nn0 = nb * 64;
  __shared__ float Lt[32][65];
  const int tid = threadIdx.x;
#pragma unroll
  for (int r = 0; r < 2; r++) {
    const int f = tid + r * 256;
    const int k = f >> 4, nc = (f & 15) * 4;
    const float4 v = *(const float4*)(src + (size_t)(k0 + k) * NDIM + nn0 + nc);
    Lt[k][nc] = v.x; Lt[k][nc + 1] = v.y; Lt[k][nc + 2] = v.z; Lt[k][nc + 3] = v.w;
  }
  __syncthreads();

  const int w = tid >> 6, lane = tid & 63;
  const int l15 = lane & 15, lg = lane >> 4;
  const int ntg = (nn0 >> 4) + w;
  u16x8 h8, l8;
#pragma unroll
  for (int j = 0; j < 8; j++) {
    const float v = Lt[lg * 8 + j][w * 16 + l15];
    const u16 hh = bf16rn(v);
    h8[j] = hh;
    l8[j] = bf16rn(v - bf16tof(hh));
  }
  const size_t base =
      ((size_t)((size_t)ei * (KDIM >> 5) + kt) * (NDIM >> 4) + ntg) * 512 +
      (size_t)lane * 8;
  *(u16x8*)(dh + base) = h8;
  *(u16x8*)(dl + base) = l8;
}

// gate+up planes: K=H=2048, N=I=1024. grid (1024, 16): 64 kt x 16 nb.
__global__ __launch_bounds__(256) void prep_gu_kernel(
    const float* __restrict__ wg, const float* __restrict__ wu,
    u16* __restrict__ bgh, u16* __restrict__ bgl,
    u16* __restrict__ buh, u16* __restrict__ bul)
{
  const int z = blockIdx.y;
  const float* src; u16 *dh, *dl;
  if (z < 8) { src = wg + (size_t)z * H * I;       dh = bgh; dl = bgl; }
  else       { src = wu + (size_t)(z - 8) * H * I; dh = buh; dl = bul; }
  prep_tile<H, I>(src, dh, dl, z & 7, blockIdx.x >> 4, blockIdx.x & 15);
}

// down planes: K=I=1024, N=H=2048. grid (1024, 8): 32 kt x 32 nb.
__global__ __launch_bounds__(256) void prep_d_kernel(
    const float* __restrict__ wd, u16* __restrict__ bdh, u16* __restrict__ bdl)
{
  const int ei = blockIdx.y;
  prep_tile<I, H>(wd + (size_t)ei * I * H, bdh, bdl, ei,
                  blockIdx.x >> 5, blockIdx.x & 31);
}

// ---------------------------------------------------------------------------
// Router (unchanged, fp32-exact selection).
// ---------------------------------------------------------------------------
__global__ __launch_bounds__(256) void router_kernel(
    const float* __restrict__ x, const float* __restrict__ rw,
    const float* __restrict__ bias, int* __restrict__ cnt,
    int* __restrict__ list, float* __restrict__ wk4,
    float* __restrict__ zerow)
{
  const int t   = blockIdx.x;
  const int tid = threadIdx.x;
  const float* xt = x + (size_t)t * H;

  float acc[NEZ];
#pragma unroll
  for (int e = 0; e < NEZ; e++) acc[e] = 0.f;

  for (int h = tid; h < H; h += 256) {
    const float xv = xt[h];
#pragma unroll
    for (int e = 0; e < NEZ; e++) acc[e] = fmaf(xv, rw[e * H + h], acc[e]);
  }

#pragma unroll
  for (int e = 0; e < NEZ; e++) {
    float v = acc[e];
#pragma unroll
    for (int off = 32; off >= 1; off >>= 1) v += __shfl_down(v, off, 64);
    acc[e] = v;
  }

  __shared__ float red[4][NEZ];
  const int wv = tid >> 6, ln = tid & 63;
  if (ln == 0) {
#pragma unroll
    for (int e = 0; e < NEZ; e++) red[wv][e] = acc[e];
  }
  __syncthreads();

  if (tid == 0) {
    float l[NEZ];
    float mx = -1e30f;
#pragma unroll
    for (int e = 0; e < NEZ; e++) {
      l[e] = red[0][e] + red[1][e] + red[2][e] + red[3][e];
      mx = fmaxf(mx, l[e]);
    }
    float s = 0.f;
#pragma unroll
    for (int e = 0; e < NEZ; e++) { l[e] = expf(l[e] - mx); s += l[e]; }
    const float inv = 1.f / s;
    float sc[NEZ], sel[NEZ];
#pragma unroll
    for (int e = 0; e < NEZ; e++) {
      sc[e]  = l[e] * inv;
      sel[e] = sc[e] + bias[e];
    }
    float zw = 0.f;
#pragma unroll
    for (int k = 0; k < TK; k++) {
      int best = 0; float bv = sel[0];
#pragma unroll
      for (int e = 1; e < NEZ; e++) {
        if (sel[e] > bv) { bv = sel[e]; best = e; }
      }
      sel[best] = -1e30f;
      const float w = sc[best];
      if (best < E) {
        const int pos = atomicAdd(&cnt[best], 1);
        list[best * T + pos] = (t << 2) | k;
        wk4[t * TK + k] = w;
      } else {
        wk4[t * TK + k] = 0.f;
        zw += w;
      }
    }
    zerow[t] = zw;
  }
}

// ---------------------------------------------------------------------------
// Gate+Up grouped GEMM. Tile 128m x 32n, 4 waves (each 32m x 32n), BK=32.
// BM=128 halves B re-reads (2 live m-blocks at ce~256); BN=32 keeps the
// stage at 24KB (A 16KB + B 8KB) -> 3 buffers = 72KB -> 2 blocks/CU.
// m innermost in the XCD chunk: the 2 B-panel sharers are dispatch-adjacent
// so the second read L2-hits. T3/T4 pipeline as round 6 (vmcnt(6), depth 2).
// Grid 2048 = 8e x (8m x 32n), XCD-chunked.
// ---------------------------------------------------------------------------
__global__ __launch_bounds__(256, 2) void gateup_kernel(
    const u16* __restrict__ xh, const u16* __restrict__ xl,
    const u16* __restrict__ bgh, const u16* __restrict__ bgl,
    const u16* __restrict__ buh, const u16* __restrict__ bul,
    const int* __restrict__ cnt, const int* __restrict__ list,
    u16* __restrict__ mid_hi, u16* __restrict__ mid_lo)
{
  const int p = blockIdx.x;
  const int L = (p & 7) * 256 + (p >> 3);   // bijective XCD-chunk remap
  const int e = L >> 8;
  const int rem = L & 255;
  const int m0 = (rem & 7) * 128;           // m innermost: sharers adjacent
  const int n0 = (rem >> 3) * 32;
  const int ce = cnt[e];
  if (m0 >= ce) return;

  __shared__ __align__(16) char lds[3 * 24 * 1024];

  const int tid = threadIdx.x;
  const int w = tid >> 6, lane = tid & 63;
  const int l15 = lane & 15, lg = lane >> 4;

  // A staging: wave w stages A-tiles a = 4w+jj (a = mt*2+pl, mt = 2w+(jj>>1))
  int ra = m0 + (2 * w) * 16 + l15;     if (ra >= ce) ra = ce - 1;
  int rb = m0 + (2 * w + 1) * 16 + l15; if (rb >= ce) rb = ce - 1;
  const int t0 = list[e * T + ra] >> 2;
  const int t1 = list[e * T + rb] >> 2;
  const char* gA0 = (const char*)(xh + (size_t)t0 * H + lg * 8);
  const char* gA1 = (const char*)(xl + (size_t)t0 * H + lg * 8);
  const char* gA2 = (const char*)(xh + (size_t)t1 * H + lg * 8);
  const char* gA3 = (const char*)(xl + (size_t)t1 * H + lg * 8);

  // B staging: wave w stages plane w, ntg_local j = 0,1
  const u16* bpl = (w == 0) ? bgh : (w == 1) ? bgl : (w == 2) ? buh : bul;
  const char* gB = (const char*)(bpl +
      ((size_t)e * 64 * 64 + (size_t)(n0 >> 4)) * 512 + (size_t)lane * 8);

  f32x4 accg[2][2] = {};
  f32x4 accu[2][2] = {};

  constexpr int KSTEPS = H / 32;   // 64

  auto stage = [&](int ts) {
    char* bb = lds + (ts % 3) * 24576;
    const int ka = ts * 64;                          // A byte advance per kt
    g2l16(gA0 + ka, bb + (w * 4 + 0) * 1024);
    g2l16(gA1 + ka, bb + (w * 4 + 1) * 1024);
    g2l16(gA2 + ka, bb + (w * 4 + 2) * 1024);
    g2l16(gA3 + ka, bb + (w * 4 + 3) * 1024);
    const char* gBs = gB + (size_t)ts * 65536;       // B byte advance per kt
    g2l16(gBs,        bb + 16384 + (0 * 4 + w) * 1024);
    g2l16(gBs + 1024, bb + 16384 + (1 * 4 + w) * 1024);
  };

  stage(0);
  stage(1);

  for (int t = 0; t < KSTEPS; t++) {
    if (t < KSTEPS - 1) { VMCNT(6); } else { VMCNT(0); }
    __builtin_amdgcn_s_barrier();
    if (t + 2 < KSTEPS) stage(t + 2);

    const char* bp = lds + (t % 3) * 24576;
    bf16x8 ah[2], al[2];
#pragma unroll
    for (int mi = 0; mi < 2; mi++) {
      const int mt = 2 * w + mi;
      ah[mi] = *(const bf16x8*)(bp + (mt * 2 + 0) * 1024 + lane * 16);
      al[mi] = *(const bf16x8*)(bp + (mt * 2 + 1) * 1024 + lane * 16);
    }
#pragma unroll
    for (int ni = 0; ni < 2; ni++) {
      const bf16x8 vgh = *(const bf16x8*)(bp + 16384 + (ni * 4 + 0) * 1024 + lane * 16);
      const bf16x8 vgl = *(const bf16x8*)(bp + 16384 + (ni * 4 + 1) * 1024 + lane * 16);
      const bf16x8 vuh = *(const bf16x8*)(bp + 16384 + (ni * 4 + 2) * 1024 + lane * 16);
      const bf16x8 vul = *(const bf16x8*)(bp + 16384 + (ni * 4 + 3) * 1024 + lane * 16);
#pragma unroll
      for (int mi = 0; mi < 2; mi++) {
        accg[mi][ni] = __builtin_amdgcn_mfma_f32_16x16x32_bf16(ah[mi], vgh, accg[mi][ni], 0, 0, 0);
        accg[mi][ni] = __builtin_amdgcn_mfma_f32_16x16x32_bf16(ah[mi], vgl, accg[mi][ni], 0, 0, 0);
        accg[mi][ni] = __builtin_amdgcn_mfma_f32_16x16x32_bf16(al[mi], vgh, accg[mi][ni], 0, 0, 0);
        accu[mi][ni] = __builtin_amdgcn_mfma_f32_16x16x32_bf16(ah[mi], vuh, accu[mi][ni], 0, 0, 0);
        accu[mi][ni] = __builtin_amdgcn_mfma_f32_16x16x32_bf16(ah[mi], vul, accu[mi][ni], 0, 0, 0);
        accu[mi][ni] = __builtin_amdgcn_mfma_f32_16x16x32_bf16(al[mi], vuh, accu[mi][ni], 0, 0, 0);
      }
    }
  }

  // epilogue: silu(g)*u -> bf16 hi/lo mid
#pragma unroll
  for (int mi = 0; mi < 2; mi++) {
#pragma unroll
    for (int rr = 0; rr < 4; rr++) {
      const int m = m0 + (2 * w + mi) * 16 + lg * 4 + rr;
      if (m >= ce) continue;
      const size_t ro = ((size_t)e * T + m) * I;
#pragma unroll
      for (int ni = 0; ni < 2; ni++) {
        const int n = n0 + ni * 16 + l15;
        const float g = accg[mi][ni][rr];
        const float u = accu[mi][ni][rr];
        const float mv = (g / (1.f + expf(-g))) * u;
        const u16 hh = bf16rn(mv);
        mid_hi[ro + n] = hh;
        mid_lo[ro + n] = bf16rn(mv - bf16tof(hh));
      }
    }
  }
}

// ---------------------------------------------------------------------------
// Down grouped GEMM: mid @ wd. Tile 128m x 64n, 4 waves (each 32m x 64n),
// BK=32, K=I (32 steps). Same 24KB stage (A 16KB + B 8KB), 3 buffers,
// vmcnt(6), 2 blocks/CU, m-innermost XCD chunking. Scatter epilogue.
// Grid 2048 = 8e x (8m x 32n).
// ---------------------------------------------------------------------------
__global__ __launch_bounds__(256, 2) void down_kernel(
    const u16* __restrict__ midh, const u16* __restrict__ midl,
    const u16* __restrict__ bdh, const u16* __restrict__ bdl,
    const int* __restrict__ cnt, const int* __restrict__ list,
    float* __restrict__ downb)
{
  const int p = blockIdx.x;
  const int L = (p & 7) * 256 + (p >> 3);
  const int e = L >> 8;
  const int rem = L & 255;
  const int m0 = (rem & 7) * 128;           // m innermost
  const int n0 = (rem >> 3) * 64;
  const int ce = cnt[e];
  if (m0 >= ce) return;

  __shared__ __align__(16) char lds[3 * 24 * 1024];

  const int tid = threadIdx.x;
  const int w = tid >> 6, lane = tid & 63;
  const int l15 = lane & 15, lg = lane >> 4;

  int ra = m0 + (2 * w) * 16 + l15;     if (ra >= ce) ra = ce - 1;
  int rb = m0 + (2 * w + 1) * 16 + l15; if (rb >= ce) rb = ce - 1;
  const char* gA0 = (const char*)(midh + ((size_t)e * T + ra) * I + lg * 8);
  const char* gA1 = (const char*)(midl + ((size_t)e * T + ra) * I + lg * 8);
  const char* gA2 = (const char*)(midh + ((size_t)e * T + rb) * I + lg * 8);
  const char* gA3 = (const char*)(midl + ((size_t)e * T + rb) * I + lg * 8);

  // B staging: wave w stages ntg_local = w, planes hi+lo
  const size_t ntg = (size_t)(n0 >> 4) + w;
  const char* gB0 = (const char*)(bdh + ((size_t)e * 32 * 128 + ntg) * 512 + (size_t)lane * 8);
  const char* gB1 = (const char*)(bdl + ((size_t)e * 32 * 128 + ntg) * 512 + (size_t)lane * 8);

  f32x4 acc[2][4] = {};

  constexpr int KSTEPS = I / 32;   // 32

  auto stage = [&](int ts) {
    char* bb = lds + (ts % 3) * 24576;
    const int ka = ts * 64;
    const size_t kb = (size_t)ts * 131072;   // 128 ntg * 1KB per kt
    g2l16(gA0 + ka, bb + (w * 4 + 0) * 1024);
    g2l16(gA1 + ka, bb + (w * 4 + 1) * 1024);
    g2l16(gA2 + ka, bb + (w * 4 + 2) * 1024);
    g2l16(gA3 + ka, bb + (w * 4 + 3) * 1024);
    g2l16(gB0 + kb, bb + 16384 + (w * 2 + 0) * 1024);
    g2l16(gB1 + kb, bb + 16384 + (w * 2 + 1) * 1024);
  };

  stage(0);
  stage(1);

  for (int t = 0; t < KSTEPS; t++) {
    if (t < KSTEPS - 1) { VMCNT(6); } else { VMCNT(0); }
    __builtin_amdgcn_s_barrier();
    if (t + 2 < KSTEPS) stage(t + 2);

    const char* bp = lds + (t % 3) * 24576;
    bf16x8 ah[2], al[2];
#pragma unroll
    for (int mi = 0; mi < 2; mi++) {
      const int mt = 2 * w + mi;
      ah[mi] = *(const bf16x8*)(bp + (mt * 2 + 0) * 1024 + lane * 16);
      al[mi] = *(const bf16x8*)(bp + (mt * 2 + 1) * 1024 + lane * 16);
    }
#pragma unroll
    for (int ni = 0; ni < 4; ni++) {
      const bf16x8 vbh = *(const bf16x8*)(bp + 16384 + (ni * 2 + 0) * 1024 + lane * 16);
      const bf16x8 vbl = *(const bf16x8*)(bp + 16384 + (ni * 2 + 1) * 1024 + lane * 16);
#pragma unroll
      for (int mi = 0; mi < 2; mi++) {
        acc[mi][ni] = __builtin_amdgcn_mfma_f32_16x16x32_bf16(ah[mi], vbh, acc[mi][ni], 0, 0, 0);
        acc[mi][ni] = __builtin_amdgcn_mfma_f32_16x16x32_bf16(ah[mi], vbl, acc[mi][ni], 0, 0, 0);
        acc[mi][ni] = __builtin_amdgcn_mfma_f32_16x16x32_bf16(al[mi], vbh, acc[mi][ni], 0, 0, 0);
      }
    }
  }

#pragma unroll
  for (int mi = 0; mi < 2; mi++) {
#pragma unroll
    for (int rr = 0; rr < 4; rr++) {
      const int m = m0 + (2 * w + mi) * 16 + lg * 4 + rr;
      if (m >= ce) continue;
      const int ent  = list[e * T + m];
      const int tok  = ent >> 2;
      const int slot = ent & 3;
      float* drow = downb + ((size_t)tok * TK + slot) * H;
#pragma unroll
      for (int ni = 0; ni < 4; ni++) {
        const int n = n0 + ni * 16 + l15;
        drow[n] = acc[mi][ni][rr];
      }
    }
  }
}

// ---------------------------------------------------------------------------
// Combine (unchanged).
// ---------------------------------------------------------------------------
__global__ __launch_bounds__(256) void combine_kernel(
    const float* __restrict__ x, const float* __restrict__ downb,
    const float* __restrict__ wk4, const float* __restrict__ zerow,
    float* __restrict__ out)
{
  const int idx = blockIdx.x * 256 + threadIdx.x;
  const int t   = idx >> 9;
  const int h   = (idx & 511) * 4;

  const float w0 = wk4[t * TK + 0];
  const float w1 = wk4[t * TK + 1];
  const float w2 = wk4[t * TK + 2];
  const float w3 = wk4[t * TK + 3];
  const float zw = zerow[t];

  const float4 xv = *(const float4*)(x + (size_t)t * H + h);
  const float4 d0 = *(const float4*)(downb + ((size_t)t * TK + 0) * H + h);
  const float4 d1 = *(const float4*)(downb + ((size_t)t * TK + 1) * H + h);
  const float4 d2 = *(const float4*)(downb + ((size_t)t * TK + 2) * H + h);
  const float4 d3 = *(const float4*)(downb + ((size_t)t * TK + 3) * H + h);

  float4 o;
  o.x = w0 * d0.x + w1 * d1.x + w2 * d2.x + w3 * d3.x + zw * xv.x;
  o.y = w0 * d0.y + w1 * d1.y + w2 * d2.y + w3 * d3.y + zw * xv.y;
  o.z = w0 * d0.z + w1 * d1.z + w2 * d2.z + w3 * d3.z + zw * xv.z;
  o.w = w0 * d0.w + w1 * d1.w + w2 * d2.w + w3 * d3.w + zw * xv.w;
  *(float4*)(out + (size_t)t * H + h) = o;
}

// ---------------------------------------------------------------------------
// Workspace plan (total ~168 MiB; aliasing is stream-order safe):
//   P region = 4 planes x 32 MiB:
//     [P+0]      bgh  -> later bdh      (prep_d runs after gateup)
//     [P+32Mi]   bgl  -> later bdl
//     [P+64Mi]   buh  -> later downb    (32 MiB exactly)
//     [P+96Mi]   bul  -> free during down
// ---------------------------------------------------------------------------
extern "C" void kernel_launch(void* const* d_in, const int* in_sizes, int n_in,
                              void* d_out, int out_size, void* d_ws, size_t ws_size,
                              hipStream_t stream) {
  const float* x    = (const float*)d_in[0];
  const float* rw   = (const float*)d_in[1];
  const float* bias = (const float*)d_in[2];
  const float* wg   = (const float*)d_in[3];
  const float* wu   = (const float*)d_in[4];
  const float* wd   = (const float*)d_in[5];
  float* out = (float*)d_out;

  char* ws = (char*)d_ws;
  size_t off = 0;
  auto alloc = [&](size_t bytes) {
    void* p = ws + off;
    off = (off + bytes + 1023) & ~(size_t)1023;
    return p;
  };
  int*   cnt   = (int*)  alloc(E * sizeof(int));
  int*   list  = (int*)  alloc((size_t)E * T * sizeof(int));
  float* wk4   = (float*)alloc((size_t)T * TK * sizeof(float));
  float* zerow = (float*)alloc((size_t)T * sizeof(float));
  u16*   xh    = (u16*)  alloc((size_t)T * H * sizeof(u16));
  u16*   xl    = (u16*)  alloc((size_t)T * H * sizeof(u16));
  constexpr size_t PLANE = (size_t)E * H * I * sizeof(u16);  // 32 MiB
  char*  P     = (char*) alloc(4 * PLANE);
  u16*   bgh   = (u16*)(P);
  u16*   bgl   = (u16*)(P + PLANE);
  u16*   buh   = (u16*)(P + 2 * PLANE);
  u16*   bul   = (u16*)(P + 3 * PLANE);
  u16*   bdh   = bgh;                    // alias: written after gateup
  u16*   bdl   = bgl;
  float* downb = (float*)(P + 2 * PLANE);  // alias buh: written during down
  u16*   midh  = (u16*)  alloc((size_t)E * T * I * sizeof(u16));
  u16*   midl  = (u16*)  alloc((size_t)E * T * I * sizeof(u16));
  (void)ws_size;

  hipMemsetAsync(cnt, 0, E * sizeof(int), stream);

  prep_x_kernel<<<(T * H / 4) / 256, 256, 0, stream>>>(x, xh, xl);
  prep_gu_kernel<<<dim3(1024, 16), 256, 0, stream>>>(
      wg, wu, bgh, bgl, buh, bul);
  router_kernel<<<T, 256, 0, stream>>>(x, rw, bias, cnt, list, wk4, zerow);

  gateup_kernel<<<2048, 256, 0, stream>>>(
      xh, xl, bgh, bgl, buh, bul, cnt, list, midh, midl);

  prep_d_kernel<<<dim3(1024, 8), 256, 0, stream>>>(wd, bdh, bdl);

  down_kernel<<<2048, 256, 0, stream>>>(
      midh, midl, bdh, bdl, cnt, list, downb);
  combine_kernel<<<(T * H / 4) / 256, 256, 0, stream>>>(
      x, downb, wk4, zerow, out);
}

// Round 8
// 267.612 us; speedup vs baseline: 1.2272x; 1.2272x over previous
//
#include <hip/hip_runtime.h>
#include <hip/hip_bf16.h>
#include <math.h>

constexpr int T   = 1024;
constexpr int H   = 2048;
constexpr int I   = 1024;
constexpr int E   = 8;
constexpr int NEZ = 16;   // E + Z
constexpr int TK  = 4;    // TOP_K

typedef short bf16x8 __attribute__((ext_vector_type(8)));
typedef float f32x4  __attribute__((ext_vector_type(4)));
typedef unsigned short u16;
typedef u16 u16x4 __attribute__((ext_vector_type(4)));
typedef u16 u16x8 __attribute__((ext_vector_type(8)));

#define VMCNT(n) asm volatile("s_waitcnt vmcnt(" #n ")" ::: "memory")

__device__ __forceinline__ u16 bf16rn(float x) {
  unsigned u = __builtin_bit_cast(unsigned, x);
  u = u + 0x7FFFu + ((u >> 16) & 1u);
  return (u16)(u >> 16);
}
__device__ __forceinline__ float bf16tof(u16 h) {
  return __builtin_bit_cast(float, (unsigned)h << 16);
}

// async global->LDS, 16B per lane; LDS dest = wave-uniform base + lane*16
__device__ __forceinline__ void g2l16(const void* g, void* l) {
  __builtin_amdgcn_global_load_lds(
      (const __attribute__((address_space(1))) unsigned int*)g,
      (__attribute__((address_space(3))) unsigned int*)l, 16, 0, 0);
}

// ---------------------------------------------------------------------------
// prep_x: split x into bf16 hi/lo planes [T][H]
// ---------------------------------------------------------------------------
__global__ __launch_bounds__(256) void prep_x_kernel(
    const float* __restrict__ x, u16* __restrict__ xh, u16* __restrict__ xl)
{
  const int idx = (blockIdx.x * 256 + threadIdx.x) * 4;
  const float4 v = *(const float4*)(x + idx);
  u16x4 h, l;
  const float vv[4] = {v.x, v.y, v.z, v.w};
#pragma unroll
  for (int i = 0; i < 4; i++) {
    const u16 hh = bf16rn(vv[i]);
    h[i] = hh;
    l[i] = bf16rn(vv[i] - bf16tof(hh));
  }
  *(u16x4*)(xh + idx) = h;
  *(u16x4*)(xl + idx) = l;
}

// ---------------------------------------------------------------------------
// Weight prep: convert+transpose one 32k x 64n tile into lane-ordered
// microtiles. Microtile (kt,ntg) = 1KB: lane L holds elems
// (n = ntg*16 + (L&15), k = kt*32 + (L>>4)*8 + j), j=0..7.
// Plane layout [e][kt][ntg][64][8].
// ---------------------------------------------------------------------------
template <int KDIM, int NDIM>
__device__ __forceinline__ void prep_tile(
    const float* __restrict__ src, u16* __restrict__ dh, u16* __restrict__ dl,
    int ei, int kt, int nb)
{
  const int k0 = kt * 32, nn0 = nb * 64;
  __shared__ float Lt[32][65];
  const int tid = threadIdx.x;
#pragma unroll
  for (int r = 0; r < 2; r++) {
    const int f = tid + r * 256;
    const int k = f >> 4, nc = (f & 15) * 4;
    const float4 v = *(const float4*)(src + (size_t)(k0 + k) * NDIM + nn0 + nc);
    Lt[k][nc] = v.x; Lt[k][nc + 1] = v.y; Lt[k][nc + 2] = v.z; Lt[k][nc + 3] = v.w;
  }
  __syncthreads();

  const int w = tid >> 6, lane = tid & 63;
  const int l15 = lane & 15, lg = lane >> 4;
  const int ntg = (nn0 >> 4) + w;
  u16x8 h8, l8;
#pragma unroll
  for (int j = 0; j < 8; j++) {
    const float v = Lt[lg * 8 + j][w * 16 + l15];
    const u16 hh = bf16rn(v);
    h8[j] = hh;
    l8[j] = bf16rn(v - bf16tof(hh));
  }
  const size_t base =
      ((size_t)((size_t)ei * (KDIM >> 5) + kt) * (NDIM >> 4) + ntg) * 512 +
      (size_t)lane * 8;
  *(u16x8*)(dh + base) = h8;
  *(u16x8*)(dl + base) = l8;
}

// gate+up planes: K=H=2048, N=I=1024. grid (1024, 16): 64 kt x 16 nb.
__global__ __launch_bounds__(256) void prep_gu_kernel(
    const float* __restrict__ wg, const float* __restrict__ wu,
    u16* __restrict__ bgh, u16* __restrict__ bgl,
    u16* __restrict__ buh, u16* __restrict__ bul)
{
  const int z = blockIdx.y;
  const float* src; u16 *dh, *dl;
  if (z < 8) { src = wg + (size_t)z * H * I;       dh = bgh; dl = bgl; }
  else       { src = wu + (size_t)(z - 8) * H * I; dh = buh; dl = bul; }
  prep_tile<H, I>(src, dh, dl, z & 7, blockIdx.x >> 4, blockIdx.x & 15);
}

// down planes: K=I=1024, N=H=2048. grid (1024, 8): 32 kt x 32 nb.
__global__ __launch_bounds__(256) void prep_d_kernel(
    const float* __restrict__ wd, u16* __restrict__ bdh, u16* __restrict__ bdl)
{
  const int ei = blockIdx.y;
  prep_tile<I, H>(wd + (size_t)ei * I * H, bdh, bdl, ei,
                  blockIdx.x >> 5, blockIdx.x & 31);
}

// ---------------------------------------------------------------------------
// Router (unchanged, fp32-exact selection).
// ---------------------------------------------------------------------------
__global__ __launch_bounds__(256) void router_kernel(
    const float* __restrict__ x, const float* __restrict__ rw,
    const float* __restrict__ bias, int* __restrict__ cnt,
    int* __restrict__ list, float* __restrict__ wk4,
    float* __restrict__ zerow)
{
  const int t   = blockIdx.x;
  const int tid = threadIdx.x;
  const float* xt = x + (size_t)t * H;

  float acc[NEZ];
#pragma unroll
  for (int e = 0; e < NEZ; e++) acc[e] = 0.f;

  for (int h = tid; h < H; h += 256) {
    const float xv = xt[h];
#pragma unroll
    for (int e = 0; e < NEZ; e++) acc[e] = fmaf(xv, rw[e * H + h], acc[e]);
  }

#pragma unroll
  for (int e = 0; e < NEZ; e++) {
    float v = acc[e];
#pragma unroll
    for (int off = 32; off >= 1; off >>= 1) v += __shfl_down(v, off, 64);
    acc[e] = v;
  }

  __shared__ float red[4][NEZ];
  const int wv = tid >> 6, ln = tid & 63;
  if (ln == 0) {
#pragma unroll
    for (int e = 0; e < NEZ; e++) red[wv][e] = acc[e];
  }
  __syncthreads();

  if (tid == 0) {
    float l[NEZ];
    float mx = -1e30f;
#pragma unroll
    for (int e = 0; e < NEZ; e++) {
      l[e] = red[0][e] + red[1][e] + red[2][e] + red[3][e];
      mx = fmaxf(mx, l[e]);
    }
    float s = 0.f;
#pragma unroll
    for (int e = 0; e < NEZ; e++) { l[e] = expf(l[e] - mx); s += l[e]; }
    const float inv = 1.f / s;
    float sc[NEZ], sel[NEZ];
#pragma unroll
    for (int e = 0; e < NEZ; e++) {
      sc[e]  = l[e] * inv;
      sel[e] = sc[e] + bias[e];
    }
    float zw = 0.f;
#pragma unroll
    for (int k = 0; k < TK; k++) {
      int best = 0; float bv = sel[0];
#pragma unroll
      for (int e = 1; e < NEZ; e++) {
        if (sel[e] > bv) { bv = sel[e]; best = e; }
      }
      sel[best] = -1e30f;
      const float w = sc[best];
      if (best < E) {
        const int pos = atomicAdd(&cnt[best], 1);
        list[best * T + pos] = (t << 2) | k;
        wk4[t * TK + k] = w;
      } else {
        wk4[t * TK + k] = 0.f;
        zw += w;
      }
    }
    zerow[t] = zw;
  }
}

// ---------------------------------------------------------------------------
// Gate+Up grouped GEMM. 512 threads, 8 waves. Tile 128m x 64n, BK=32.
// Wave grid 4wm x 2wn: each wave 32m x 32n (2x2 fragments, g+u).
// Stage 32KB/step (A 16KB hi/lo + B 16KB 4 planes); 3 bufs = 96KB, 1 blk/CU.
// Counted vmcnt depth-2 pipeline. mid written in microtile layout
// [e][ktI 32][mtg 64][lane 64][8] so down stages A contiguously.
// Grid 1024 = 8e x (8m x 16n), XCD-chunked, m innermost (live-first + B pair
// L2 reuse).
// ---------------------------------------------------------------------------
__global__ __launch_bounds__(512, 1) void gateup_kernel(
    const u16* __restrict__ xh, const u16* __restrict__ xl,
    const u16* __restrict__ bgh, const u16* __restrict__ bgl,
    const u16* __restrict__ buh, const u16* __restrict__ bul,
    const int* __restrict__ cnt, const int* __restrict__ list,
    u16* __restrict__ midh, u16* __restrict__ midl)
{
  const int p = blockIdx.x;
  const int L = (p & 7) * 128 + (p >> 3);   // XCD chunk == expert
  const int e = L >> 7;
  const int rem = L & 127;
  const int m0 = (rem & 7) * 128;           // m innermost
  const int n0 = (rem >> 3) * 64;
  const int ce = cnt[e];
  if (m0 >= ce) return;

  __shared__ __align__(16) char lds[3 * 32 * 1024];

  const int tid = threadIdx.x;
  const int w = tid >> 6, lane = tid & 63;
  const int l15 = lane & 15, lg = lane >> 4;
  const int wm = w >> 1, wn = w & 1;

  // A staging: wave w stages m-tile mt = w (rows m0 + w*16 + l15), hi+lo
  int ra = m0 + w * 16 + l15; if (ra >= ce) ra = ce - 1;
  const int tok = list[e * T + ra] >> 2;
  const char* gAh = (const char*)(xh + (size_t)tok * H + lg * 8);
  const char* gAl = (const char*)(xl + (size_t)tok * H + lg * 8);

  // B staging: wave w stages ntg_local = w>>1, planes (gh,gl) if w even,
  // (uh,ul) if odd. LDS B slot = (ntg*4 + plane)*1KB, plane order gh,gl,uh,ul.
  const u16* bp0 = (w & 1) ? buh : bgh;
  const u16* bp1 = (w & 1) ? bul : bgl;
  const size_t ntgl = (size_t)(n0 >> 4) + (w >> 1);
  const char* gB0 = (const char*)(bp0 + ((size_t)e * 64 * 64 + ntgl) * 512 + (size_t)lane * 8);
  const char* gB1 = (const char*)(bp1 + ((size_t)e * 64 * 64 + ntgl) * 512 + (size_t)lane * 8);
  const int dstB0 = 16384 + ((w >> 1) * 4 + (w & 1) * 2) * 1024;

  f32x4 accg[2][2] = {};
  f32x4 accu[2][2] = {};

  constexpr int KSTEPS = H / 32;   // 64

  auto stage = [&](int ts) {
    char* bb = lds + (ts % 3) * 32768;
    const int ka = ts * 64;                    // A byte advance per kt
    const size_t kb = (size_t)ts * 65536;      // B byte advance per kt (64 ntg * 1KB)
    g2l16(gAh + ka, bb + (w * 2 + 0) * 1024);
    g2l16(gAl + ka, bb + (w * 2 + 1) * 1024);
    g2l16(gB0 + kb, bb + dstB0);
    g2l16(gB1 + kb, bb + dstB0 + 1024);
  };

  stage(0);
  stage(1);

  for (int t = 0; t < KSTEPS; t++) {
    if (t < KSTEPS - 1) { VMCNT(4); } else { VMCNT(0); }
    __builtin_amdgcn_s_barrier();
    if (t + 2 < KSTEPS) stage(t + 2);

    const char* bp = lds + (t % 3) * 32768;
    bf16x8 ah[2], al[2];
#pragma unroll
    for (int mi = 0; mi < 2; mi++) {
      const int mt = wm * 2 + mi;
      ah[mi] = *(const bf16x8*)(bp + (mt * 2 + 0) * 1024 + lane * 16);
      al[mi] = *(const bf16x8*)(bp + (mt * 2 + 1) * 1024 + lane * 16);
    }
#pragma unroll
    for (int ni = 0; ni < 2; ni++) {
      const int nt = wn * 2 + ni;
      const bf16x8 vgh = *(const bf16x8*)(bp + 16384 + (nt * 4 + 0) * 1024 + lane * 16);
      const bf16x8 vgl = *(const bf16x8*)(bp + 16384 + (nt * 4 + 1) * 1024 + lane * 16);
      const bf16x8 vuh = *(const bf16x8*)(bp + 16384 + (nt * 4 + 2) * 1024 + lane * 16);
      const bf16x8 vul = *(const bf16x8*)(bp + 16384 + (nt * 4 + 3) * 1024 + lane * 16);
#pragma unroll
      for (int mi = 0; mi < 2; mi++) {
        accg[mi][ni] = __builtin_amdgcn_mfma_f32_16x16x32_bf16(ah[mi], vgh, accg[mi][ni], 0, 0, 0);
        accg[mi][ni] = __builtin_amdgcn_mfma_f32_16x16x32_bf16(ah[mi], vgl, accg[mi][ni], 0, 0, 0);
        accg[mi][ni] = __builtin_amdgcn_mfma_f32_16x16x32_bf16(al[mi], vgh, accg[mi][ni], 0, 0, 0);
        accu[mi][ni] = __builtin_amdgcn_mfma_f32_16x16x32_bf16(ah[mi], vuh, accu[mi][ni], 0, 0, 0);
        accu[mi][ni] = __builtin_amdgcn_mfma_f32_16x16x32_bf16(ah[mi], vul, accu[mi][ni], 0, 0, 0);
        accu[mi][ni] = __builtin_amdgcn_mfma_f32_16x16x32_bf16(al[mi], vuh, accu[mi][ni], 0, 0, 0);
      }
    }
  }

  // epilogue: silu(g)*u -> bf16 hi/lo mid in microtile layout
  // elem (m, n): kt = n>>5, mtg = m>>4, lane2 = (m&15) + ((n>>3)&3)*16, j = n&7
#pragma unroll
  for (int mi = 0; mi < 2; mi++) {
#pragma unroll
    for (int rr = 0; rr < 4; rr++) {
      const int m = m0 + (wm * 2 + mi) * 16 + lg * 4 + rr;
      if (m >= ce) continue;
#pragma unroll
      for (int ni = 0; ni < 2; ni++) {
        const int n = n0 + (wn * 2 + ni) * 16 + l15;
        const float g = accg[mi][ni][rr];
        const float u = accu[mi][ni][rr];
        const float mv = (g / (1.f + expf(-g))) * u;
        const u16 hh = bf16rn(mv);
        const int kt = n >> 5, mtg = m >> 4;
        const int ln2 = (m & 15) + ((n >> 3) & 3) * 16;
        const size_t off =
            (((size_t)e * 32 + kt) * 64 + mtg) * 512 + (size_t)ln2 * 8 + (n & 7);
        midh[off] = hh;
        midl[off] = bf16rn(mv - bf16tof(hh));
      }
    }
  }
}

// ---------------------------------------------------------------------------
// Down grouped GEMM: mid (microtile planes) @ wd planes. 512 threads, 8 waves.
// Tile 128m x 128n, BK=32, K=I (32 steps). Wave grid 2wm x 4wn: each wave
// 64m x 32n (4x2 fragments). Stage 32KB (A 16 + B 16); 3 bufs = 96KB,
// 1 blk/CU. A staging is contiguous 1KB microtile loads (no gather).
// Grid 1024 = 8e x (8m x 16n), XCD-chunked, m innermost. Scatter epilogue.
// ---------------------------------------------------------------------------
__global__ __launch_bounds__(512, 1) void down_kernel(
    const u16* __restrict__ midh, const u16* __restrict__ midl,
    const u16* __restrict__ bdh, const u16* __restrict__ bdl,
    const int* __restrict__ cnt, const int* __restrict__ list,
    float* __restrict__ downb)
{
  const int p = blockIdx.x;
  const int L = (p & 7) * 128 + (p >> 3);
  const int e = L >> 7;
  const int rem = L & 127;
  const int m0 = (rem & 7) * 128;           // m innermost
  const int n0 = (rem >> 3) * 128;
  const int ce = cnt[e];
  if (m0 >= ce) return;

  __shared__ __align__(16) char lds[3 * 32 * 1024];

  const int tid = threadIdx.x;
  const int w = tid >> 6, lane = tid & 63;
  const int l15 = lane & 15, lg = lane >> 4;
  const int wm = w >> 2, wn = w & 3;

  // A staging: wave w stages mtg-tile (m0/16 + w), hi+lo (contiguous 1KB)
  const size_t mtg0 = (size_t)(m0 >> 4) + w;
  const char* gAh = (const char*)(midh + ((size_t)e * 32 * 64 + mtg0) * 512 + (size_t)lane * 8);
  const char* gAl = (const char*)(midl + ((size_t)e * 32 * 64 + mtg0) * 512 + (size_t)lane * 8);
  // B staging: wave w stages ntg-tile (n0/16 + w), hi+lo
  const size_t ntg0 = (size_t)(n0 >> 4) + w;
  const char* gBh = (const char*)(bdh + ((size_t)e * 32 * 128 + ntg0) * 512 + (size_t)lane * 8);
  const char* gBl = (const char*)(bdl + ((size_t)e * 32 * 128 + ntg0) * 512 + (size_t)lane * 8);

  f32x4 acc[4][2] = {};

  constexpr int KSTEPS = I / 32;   // 32

  auto stage = [&](int ts) {
    char* bb = lds + (ts % 3) * 32768;
    const size_t ka = (size_t)ts * 65536;    // A advance per kt (64 mtg * 1KB)
    const size_t kb = (size_t)ts * 131072;   // B advance per kt (128 ntg * 1KB)
    g2l16(gAh + ka, bb + (w * 2 + 0) * 1024);
    g2l16(gAl + ka, bb + (w * 2 + 1) * 1024);
    g2l16(gBh + kb, bb + 16384 + (w * 2 + 0) * 1024);
    g2l16(gBl + kb, bb + 16384 + (w * 2 + 1) * 1024);
  };

  stage(0);
  stage(1);

  for (int t = 0; t < KSTEPS; t++) {
    if (t < KSTEPS - 1) { VMCNT(4); } else { VMCNT(0); }
    __builtin_amdgcn_s_barrier();
    if (t + 2 < KSTEPS) stage(t + 2);

    const char* bp = lds + (t % 3) * 32768;
    bf16x8 ah[4], al[4];
#pragma unroll
    for (int mi = 0; mi < 4; mi++) {
      const int mt = wm * 4 + mi;
      ah[mi] = *(const bf16x8*)(bp + (mt * 2 + 0) * 1024 + lane * 16);
      al[mi] = *(const bf16x8*)(bp + (mt * 2 + 1) * 1024 + lane * 16);
    }
#pragma unroll
    for (int ni = 0; ni < 2; ni++) {
      const int nt = wn * 2 + ni;
      const bf16x8 vbh = *(const bf16x8*)(bp + 16384 + (nt * 2 + 0) * 1024 + lane * 16);
      const bf16x8 vbl = *(const bf16x8*)(bp + 16384 + (nt * 2 + 1) * 1024 + lane * 16);
#pragma unroll
      for (int mi = 0; mi < 4; mi++) {
        acc[mi][ni] = __builtin_amdgcn_mfma_f32_16x16x32_bf16(ah[mi], vbh, acc[mi][ni], 0, 0, 0);
        acc[mi][ni] = __builtin_amdgcn_mfma_f32_16x16x32_bf16(ah[mi], vbl, acc[mi][ni], 0, 0, 0);
        acc[mi][ni] = __builtin_amdgcn_mfma_f32_16x16x32_bf16(al[mi], vbh, acc[mi][ni], 0, 0, 0);
      }
    }
  }

#pragma unroll
  for (int mi = 0; mi < 4; mi++) {
#pragma unroll
    for (int rr = 0; rr < 4; rr++) {
      const int m = m0 + (wm * 4 + mi) * 16 + lg * 4 + rr;
      if (m >= ce) continue;
      const int ent  = list[e * T + m];
      const int tok  = ent >> 2;
      const int slot = ent & 3;
      float* drow = downb + ((size_t)tok * TK + slot) * H;
#pragma unroll
      for (int ni = 0; ni < 2; ni++) {
        const int n = n0 + (wn * 2 + ni) * 16 + l15;
        drow[n] = acc[mi][ni][rr];
      }
    }
  }
}

// ---------------------------------------------------------------------------
// Combine (unchanged).
// ---------------------------------------------------------------------------
__global__ __launch_bounds__(256) void combine_kernel(
    const float* __restrict__ x, const float* __restrict__ downb,
    const float* __restrict__ wk4, const float* __restrict__ zerow,
    float* __restrict__ out)
{
  const int idx = blockIdx.x * 256 + threadIdx.x;
  const int t   = idx >> 9;
  const int h   = (idx & 511) * 4;

  const float w0 = wk4[t * TK + 0];
  const float w1 = wk4[t * TK + 1];
  const float w2 = wk4[t * TK + 2];
  const float w3 = wk4[t * TK + 3];
  const float zw = zerow[t];

  const float4 xv = *(const float4*)(x + (size_t)t * H + h);
  const float4 d0 = *(const float4*)(downb + ((size_t)t * TK + 0) * H + h);
  const float4 d1 = *(const float4*)(downb + ((size_t)t * TK + 1) * H + h);
  const float4 d2 = *(const float4*)(downb + ((size_t)t * TK + 2) * H + h);
  const float4 d3 = *(const float4*)(downb + ((size_t)t * TK + 3) * H + h);

  float4 o;
  o.x = w0 * d0.x + w1 * d1.x + w2 * d2.x + w3 * d3.x + zw * xv.x;
  o.y = w0 * d0.y + w1 * d1.y + w2 * d2.y + w3 * d3.y + zw * xv.y;
  o.z = w0 * d0.z + w1 * d1.z + w2 * d2.z + w3 * d3.z + zw * xv.z;
  o.w = w0 * d0.w + w1 * d1.w + w2 * d2.w + w3 * d3.w + zw * xv.w;
  *(float4*)(out + (size_t)t * H + h) = o;
}

// ---------------------------------------------------------------------------
// Workspace plan (total ~168 MiB; aliasing is stream-order safe):
//   P region = 4 planes x 32 MiB:
//     [P+0]      bgh  -> later bdh      (prep_d runs after gateup)
//     [P+32Mi]   bgl  -> later bdl
//     [P+64Mi]   buh  -> later downb    (32 MiB exactly)
//     [P+96Mi]   bul  -> free during down
// ---------------------------------------------------------------------------
extern "C" void kernel_launch(void* const* d_in, const int* in_sizes, int n_in,
                              void* d_out, int out_size, void* d_ws, size_t ws_size,
                              hipStream_t stream) {
  const float* x    = (const float*)d_in[0];
  const float* rw   = (const float*)d_in[1];
  const float* bias = (const float*)d_in[2];
  const float* wg   = (const float*)d_in[3];
  const float* wu   = (const float*)d_in[4];
  const float* wd   = (const float*)d_in[5];
  float* out = (float*)d_out;

  char* ws = (char*)d_ws;
  size_t off = 0;
  auto alloc = [&](size_t bytes) {
    void* p = ws + off;
    off = (off + bytes + 1023) & ~(size_t)1023;
    return p;
  };
  int*   cnt   = (int*)  alloc(E * sizeof(int));
  int*   list  = (int*)  alloc((size_t)E * T * sizeof(int));
  float* wk4   = (float*)alloc((size_t)T * TK * sizeof(float));
  float* zerow = (float*)alloc((size_t)T * sizeof(float));
  u16*   xh    = (u16*)  alloc((size_t)T * H * sizeof(u16));
  u16*   xl    = (u16*)  alloc((size_t)T * H * sizeof(u16));
  constexpr size_t PLANE = (size_t)E * H * I * sizeof(u16);  // 32 MiB
  char*  P     = (char*) alloc(4 * PLANE);
  u16*   bgh   = (u16*)(P);
  u16*   bgl   = (u16*)(P + PLANE);
  u16*   buh   = (u16*)(P + 2 * PLANE);
  u16*   bul   = (u16*)(P + 3 * PLANE);
  u16*   bdh   = bgh;                    // alias: written after gateup
  u16*   bdl   = bgl;
  float* downb = (float*)(P + 2 * PLANE);  // alias buh: written during down
  u16*   midh  = (u16*)  alloc((size_t)E * T * I * sizeof(u16));  // microtile layout
  u16*   midl  = (u16*)  alloc((size_t)E * T * I * sizeof(u16));
  (void)ws_size;

  hipMemsetAsync(cnt, 0, E * sizeof(int), stream);

  prep_x_kernel<<<(T * H / 4) / 256, 256, 0, stream>>>(x, xh, xl);
  prep_gu_kernel<<<dim3(1024, 16), 256, 0, stream>>>(
      wg, wu, bgh, bgl, buh, bul);
  router_kernel<<<T, 256, 0, stream>>>(x, rw, bias, cnt, list, wk4, zerow);

  gateup_kernel<<<1024, 512, 0, stream>>>(
      xh, xl, bgh, bgl, buh, bul, cnt, list, midh, midl);

  prep_d_kernel<<<dim3(1024, 8), 256, 0, stream>>>(wd, bdh, bdl);

  down_kernel<<<1024, 512, 0, stream>>>(
      midh, midl, bdh, bdl, cnt, list, downb);
  combine_kernel<<<(T * H / 4) / 256, 256, 0, stream>>>(
      x, downb, wk4, zerow, out);
}